// Round 8
// baseline (135.919 us; speedup 1.0000x reference)
//
#include <hip/hip_runtime.h>

namespace {

typedef float v2f __attribute__((ext_vector_type(2)));

constexpr int kW = 640;
constexpr unsigned kSpan = 230400u;   // 360*640
constexpr int kB1 = 900;              // stats blocks (256 pts each)
constexpr int kB3 = 2048;             // count blocks: 1024 point-blocks x 2 plane-halves
constexpr int kPPB3 = 225;            // points per count block
constexpr int kB5 = 900;              // zc blocks (256 pts each)

// ws layout (bytes) — all handoffs are cross-kernel (stream-ordered), plain stores
// ws_size = 256 MiB (fill counter evidence); we use < 8 MiB.
constexpr size_t kOffMaxv    = 0;     // int, atomicMax accumulator of float bits
constexpr size_t kOffL17     = 8;     // f64 loss17
constexpr size_t kOffSel     = 16;    // u32 selkey (atomicMax in k_select)
constexpr size_t kOffPlanes  = 512;                      // 1024 * 16 = 16384
constexpr size_t kOffSP      = 512 + 16384;              // 900 * 48 = 43200
constexpr size_t kOffZP      = 61440;                    // 900 * 32 = 28800
constexpr size_t kOffPts     = 2097152;                  // pts: 230400*16 = 3.69 MB
constexpr size_t kOffPartial = 6291456;                  // 2048 * 256 * 4 = 2 MB

__device__ __forceinline__ unsigned rotl32(unsigned v, int r) {
  return (v << r) | (v >> (32 - r));
}

// Threefry-2x32, 20 rounds, key = (0, 42)  [jax.random.key(42)]
__device__ __forceinline__ void threefry(unsigned c0, unsigned c1,
                                         unsigned& o0, unsigned& o1) {
  const unsigned ks0 = 0u, ks1 = 42u, ks2 = 0x1BD11BDAu ^ 0u ^ 42u;
  unsigned x0 = c0 + ks0, x1 = c1 + ks1;
#define TFR(r) { x0 += x1; x1 = rotl32(x1, (r)); x1 ^= x0; }
  TFR(13) TFR(15) TFR(26) TFR(6)
  x0 += ks1; x1 += ks2 + 1u;
  TFR(17) TFR(29) TFR(16) TFR(24)
  x0 += ks2; x1 += ks0 + 2u;
  TFR(13) TFR(15) TFR(26) TFR(6)
  x0 += ks0; x1 += ks1 + 3u;
  TFR(17) TFR(29) TFR(16) TFR(24)
  x0 += ks1; x1 += ks2 + 4u;
  TFR(13) TFR(15) TFR(26) TFR(6)
  x0 += ks2; x1 += ks0 + 5u;
#undef TFR
  o0 = x0; o1 = x1;
}

__device__ __forceinline__ void pix_coords(float d, int row, int col, bool& valid,
                                           float& x, float& y, float& z) {
  valid = (d > 0.0f) && (d < 65535.0f);
  float z0 = d / 1000.0f;
  float x0 = z0 * ((float)col - 334.081f) / 460.585f;
  float y0 = z0 * ((float)row - 169.808f) / 460.268f;
  x = x0 * 1000.0f;
  y = y0 * 1000.0f;
  z = z0 * 1000.0f;
  if (x == 0.0f) x = 1e-7f;
  if (y == 0.0f) y = 1e-7f;
  if (z == 0.0f) z = 1e-7f;
}

// normalized point — identical expression wherever used (bitwise mask consistency)
__device__ __forceinline__ void make_pt(float d, int row, int col, float maxv,
                                        float& x, float& y, float& z) {
  bool v; float a, b, c;
  pix_coords(d, row, col, v, a, b, c);
  x = (v ? a : 0.f) / maxv;
  y = (v ? b : 0.f) / maxv;
  z = (v ? c : 0.f) / maxv;
}

__device__ __forceinline__ float get_thresh(int ep) {
  return (float)fmax(0.025 - 0.001 * (double)ep, 0.005);
}

// ===== K1: stats partials (plain stores) + raw pts + atomicMax maxv; ALL exit =====
__global__ __launch_bounds__(256) void k_stats(const float* __restrict__ fake,
                                               const float* __restrict__ real,
                                               char* __restrict__ ws) {
  int* maxvBits = (int*)(ws + kOffMaxv);
  double* sp = (double*)(ws + kOffSP);
  float4* ptsraw = (float4*)(ws + kOffPts);

  const int b = blockIdx.x, t = threadIdx.x;
  const int lane = t & 63, wid = t >> 6;

  __shared__ double sD0[4], sD1[4], sD2[4], sD3[4];
  __shared__ int sI0[4];
  __shared__ float sF0[4];

  int i = b * 256 + t;
  int row = i / kW, col = i - row * kW;
  bool vr, vf; float rx, ry, rz, fx, fy, fz;
  pix_coords(real[i], row, col, vr, rx, ry, rz);
  pix_coords(fake[i], row, col, vf, fx, fy, fz);
  // consumed only by later kernels (stream order) => plain store
  ptsraw[i] = make_float4(vf ? fx : 0.f, vf ? fy : 0.f, vf ? fz : 0.f, 0.f);
  double dx2 = 0, dy2 = 0, dz2 = 0, dl2 = 0; int cc = 0;
  if (vr && vf) {
    float ddx = rx - fx, ddy = ry - fy, ddz = rz - fz;
    dx2 = (double)ddx * (double)ddx;
    dy2 = (double)ddy * (double)ddy;
    dz2 = (double)ddz * (double)ddz;
    double dl = log(fabs((double)rz)) - log(fabs((double)fz));
    dl2 = dl * dl;
    cc = 1;
  }
  float mx = vf ? fmaxf(fmaxf(fx, fy), fz) : 0.0f;
  for (int o = 32; o; o >>= 1) {
    dx2 += __shfl_down(dx2, o); dy2 += __shfl_down(dy2, o);
    dz2 += __shfl_down(dz2, o); dl2 += __shfl_down(dl2, o);
    cc += __shfl_down(cc, o);
    mx = fmaxf(mx, __shfl_down(mx, o));
  }
  if (lane == 0) { sD0[wid]=dx2; sD1[wid]=dy2; sD2[wid]=dz2; sD3[wid]=dl2;
                   sI0[wid]=cc; sF0[wid]=mx; }
  __syncthreads();
  if (t == 0) {
    double* e = sp + (size_t)b * 6;
    e[0] = sD0[0]+sD0[1]+sD0[2]+sD0[3];
    e[1] = sD1[0]+sD1[1]+sD1[2]+sD1[3];
    e[2] = sD2[0]+sD2[1]+sD2[2]+sD2[3];
    e[3] = sD3[0]+sD3[1]+sD3[2]+sD3[3];
    e[4] = (double)(sI0[0]+sI0[1]+sI0[2]+sI0[3]);
    float bm = fmaxf(fmaxf(sF0[0], sF0[1]), fmaxf(sF0[2], sF0[3]));
    // non-negative float bits as signed int: max is order-independent;
    // ws poison 0xAAAAAAAA is negative as signed => any candidate wins.
    atomicMax(maxvBits, (int)__float_as_uint(bm));
  }
}

// ===== K2: blocks 0..15 = planes (3-way gather split, 64 planes/block);
//           block 16 = f64 scalar reduce + out[0..3,5];
//           blocks 17..916 = normalize pts IN-PLACE (raw/maxv, division once) =====
__global__ __launch_bounds__(256) void k_mid(const float* __restrict__ fake,
                                             float* __restrict__ out,
                                             char* __restrict__ ws) {
  const int* maxvBits = (const int*)(ws + kOffMaxv);
  double* loss17p = (double*)(ws + kOffL17);
  unsigned* selkeyp = (unsigned*)(ws + kOffSel);
  float4* planes = (float4*)(ws + kOffPlanes);
  const double* sp = (const double*)(ws + kOffSP);
  float4* pts = (float4*)(ws + kOffPts);

  const int t = threadIdx.x;
  const int lane = t & 63, wid = t >> 6;

  if (blockIdx.x >= 17) {
    // ---- normalize in place: each thread owns one element (no races);
    //      consumers are later kernels only. Same division expression as before. ----
    const float maxv = __uint_as_float((unsigned)*maxvBits);
    int i = (blockIdx.x - 17) * 256 + t;
    float4 r = pts[i];
    pts[i] = make_float4(r.x / maxv, r.y / maxv, r.z / maxv, 0.f);
  } else if (blockIdx.x == 16) {
    // ---- scalar reduce: identical accumulation order to the proven version ----
    __shared__ double sD0[4], sD1[4], sD2[4], sD3[4];
    __shared__ int sI0[4];
    double gx = 0, gy = 0, gz = 0, gl = 0; int gc = 0;
    for (int r = t; r < kB1; r += 256) {
      const double* e = sp + (size_t)r * 6;
      gx += e[0]; gy += e[1]; gz += e[2]; gl += e[3];
      gc += (int)e[4];
    }
    for (int o = 32; o; o >>= 1) {
      gx += __shfl_down(gx, o); gy += __shfl_down(gy, o);
      gz += __shfl_down(gz, o); gl += __shfl_down(gl, o);
      gc += __shfl_down(gc, o);
    }
    if (lane == 0) { sD0[wid]=gx; sD1[wid]=gy; sD2[wid]=gz; sD3[wid]=gl; sI0[wid]=gc; }
    __syncthreads();
    if (t == 0) {
      double SX = sD0[0]+sD0[1]+sD0[2]+sD0[3];
      double SY = sD1[0]+sD1[1]+sD1[2]+sD1[3];
      double SZ = sD2[0]+sD2[1]+sD2[2]+sD2[3];
      double SL = sD3[0]+sD3[1]+sD3[2]+sD3[3];
      int CN = sI0[0]+sI0[1]+sI0[2]+sI0[3];
      double cntd = (CN > 0) ? (double)CN : 1.0;
      double lossX = sqrt(SX / cntd);
      double lossY = sqrt(SY / cntd);
      double lossZ = sqrt(SZ / cntd);
      double rmse_log = 10000.0 * sqrt(SL / cntd);
      double loss17 = rmse_log * fabs(10.0 * (3.0 - exp(lossX) - exp(lossY) - exp(lossZ)));
      *loss17p = loss17;
      *selkeyp = 0u;                  // atomicMax target for k_select
      out[0] = (float)rmse_log;
      out[1] = (float)lossX;
      out[2] = (float)lossY;
      out[3] = (float)lossZ;
      out[5] = (float)loss17;
    }
  } else {
    // ---- planes: 64 per block; 192 gather threads (one (pid,v) each) ----
    const float maxv = __uint_as_float((unsigned)*maxvBits);
    __shared__ float sX[192], sY[192], sZ[192];
    if (t < 192) {
      int j = t / 3;                        // 0..63 local plane
      int v = t - j * 3;                    // 0..2 vertex
      int pid = blockIdx.x * 64 + j;        // 0..1023
      if (pid < 1000) {
        unsigned p = 3u * (unsigned)pid + (unsigned)v;
        unsigned o0, o1;
        threefry(p, p + 3000u, o0, o1);     // JAX randint: o1 % span
        unsigned idx = o1 % kSpan;
        int row = (int)(idx / kW), col = (int)idx - row * kW;
        float x, y, z;
        make_pt(fake[idx], row, col, maxv, x, y, z);
        sX[t] = x; sY[t] = y; sZ[t] = z;
      }
    }
    __syncthreads();
    if (t < 64) {
      int pid = blockIdx.x * 64 + t;
      if (pid < 1000) {
        float px[3], py[3], pz[3];
#pragma unroll
        for (int v = 0; v < 3; v++) {
          px[v] = sX[3 * t + v]; py[v] = sY[3 * t + v]; pz[v] = sZ[3 * t + v];
        }
        float ax = px[1]-px[0], ay = py[1]-py[0], az = pz[1]-pz[0];
        float bx = px[2]-px[0], by = py[2]-py[0], bz = pz[2]-pz[0];
        float nx = ay*bz - az*by;
        float ny = az*bx - ax*bz;
        float nz = ax*by - ay*bx;
        float nn = sqrtf(nx*nx + ny*ny + nz*nz);
        nx /= nn; ny /= nn; nz /= nn;
        float kk = -(nx*px[1] + ny*py[1] + nz*pz[1]);
        planes[pid] = make_float4(nx, ny, nz, kk);   // next-kernel consumer => plain
      } else {
        planes[pid] = make_float4(0.f, 0.f, 0.f, 3e38f);  // dummy: never an inlier
      }
    }
  }
}

// ===== K3: plane-split count; 2048 blocks (1024 pt-blocks x 2 halves), 2 planes/thread,
//           NO LDS, wave-uniform point loads; 8 blocks/CU => 32 waves/CU =====
__global__ __launch_bounds__(256) void k_count(const int* __restrict__ epoch,
                                               const float4* __restrict__ planes,
                                               const float4* __restrict__ pts,
                                               unsigned* __restrict__ partial) {
  const int b = blockIdx.x, t = threadIdx.x;
  const int pb = b >> 1, ph = b & 1;       // point-block, plane-half
  const float th = get_thresh(*epoch);

  // each thread owns 2 planes (one v2f pair)
  int pid = ph * 512 + t * 2;
  float4 p0 = planes[pid + 0], p1 = planes[pid + 1];
  v2f Ax = {p0.x, p1.x}, Ay = {p0.y, p1.y}, Az = {p0.z, p1.z}, Aw = {p0.w, p1.w};

  const float4* __restrict__ base = pts + pb * kPPB3;

  int c0 = 0, c1 = 0;
#pragma unroll 5
  for (int s = 0; s < kPPB3; ++s) {
    float4 q = base[s];                    // wave-uniform address -> scalar/broadcast load
    v2f qx = {q.x, q.x}, qy = {q.y, q.y}, qz = {q.z, q.z};
    // per-half chain == fmaf(qx, a, fmaf(qy, b, fmaf(qz, c, d))) — matches k_zc
    v2f dA = __builtin_elementwise_fma(qx, Ax,
             __builtin_elementwise_fma(qy, Ay,
             __builtin_elementwise_fma(qz, Az, Aw)));
    c0 += (fabsf(dA.x) <= th) ? 1 : 0;
    c1 += (fabsf(dA.y) <= th) ? 1 : 0;
  }
  // counts <= 225; pack 2 x u16; one plain store (consumer is next kernel)
  partial[b * 256 + t] = (unsigned)c0 | ((unsigned)c1 << 16);
}

// ===== K4: select over plane-split partials (16 blocks x 64 planes) =====
__global__ __launch_bounds__(256) void k_select(char* __restrict__ ws) {
  unsigned* selkeyp = (unsigned*)(ws + kOffSel);
  const unsigned* partial = (const unsigned*)(ws + kOffPartial);

  const int r = blockIdx.x;             // 0..15: planes r*64 .. r*64+63
  const int t = threadIdx.x;

  __shared__ unsigned sAcc[64][5];      // padded: conflict-light

  int l = t & 63;                       // local plane
  int chunk = t >> 6;                   // 0..3: 256 point-blocks each
  int p = r * 64 + l;
  int ph = p >> 9;                      // plane-half
  int to = (p & 511) >> 1;              // owner thread in count block
  int j = p & 1;                        // u16 slot
  unsigned cnt = 0;
  for (int pb = chunk * 256; pb < chunk * 256 + 256; ++pb) {
    unsigned v = partial[(pb * 2 + ph) * 256 + to];
    cnt += (v >> (16 * j)) & 0xFFFFu;
  }
  sAcc[l][chunk] = cnt;
  __syncthreads();

  unsigned mykey = 0u;
  if (t < 64) {                         // wave 0 finalizes
    unsigned tot = sAcc[t][0] + sAcc[t][1] + sAcc[t][2] + sAcc[t][3];
    int p2 = r * 64 + t;
    if (p2 < 1000) {
      int score = ((int)tot > 5000) ? (int)tot : -1;   // MIN_POINTS, strict >
      mykey = ((unsigned)(score + 2) << 10) | (unsigned)(1023 - p2);
    }
  }
  for (int o = 32; o; o >>= 1) {
    unsigned other = __shfl_down(mykey, o);
    mykey = other > mykey ? other : mykey;
  }
  if (t == 0) atomicMax(selkeyp, mykey);
}

// ===== K5: zc partials over best plane's inliers (pre-normalized pts); ALL exit =====
__global__ __launch_bounds__(256) void k_zc(const int* __restrict__ epoch,
                                            char* __restrict__ ws) {
  const float4* planes = (const float4*)(ws + kOffPlanes);
  unsigned long long* zp = (unsigned long long*)(ws + kOffZP);
  const float4* pts = (const float4*)(ws + kOffPts);

  const int b = blockIdx.x, t = threadIdx.x;
  const int lane = t & 63, wid = t >> 6;
  const float th = get_thresh(*epoch);

  // best plane + rotation derived per block (cheap, uniform; cross-kernel plain loads)
  unsigned selkey = *(const unsigned*)(ws + kOffSel);
  int best = 1023 - (int)(selkey & 1023u);
  float4 pl = planes[best];
  const float a = pl.x, bb = pl.y, c = pl.z, d = pl.w;
  float n2 = a * a + bb * bb + c * c;
  float cos_t = c / sqrtf(n2);
  float sin_t = sqrtf((a * a + bb * bb) / n2);
  float sab = sqrtf(a * a + bb * bb);
  float u1 = bb / sab, u2 = -a / sab;
  const float r0 = -u2 * sin_t, r1 = u1 * sin_t, r2 = cos_t, tz = d / c;

  __shared__ double sD0[4];
  __shared__ int sI0[4];
  __shared__ float sF0[4], sF1[4];

  double sz = 0.0; int ic = 0; float zmx = -INFINITY, zmn = -INFINITY;  // zmn = max(-zc)
  {
    float4 q = pts[b * 256 + t];   // already normalized (same bits as before)
    // identical per-lane chain to k_count's pk_fma halves
    float dist = fmaf(q.x, a, fmaf(q.y, bb, fmaf(q.z, c, d)));
    if (fabsf(dist) <= th) {
      float zc = fmaf(q.x, r0, fmaf(q.y, r1, (q.z + tz) * r2));
      sz = (double)zc; ic = 1; zmx = zc; zmn = -zc;
    }
  }
  for (int o = 32; o; o >>= 1) {
    sz += __shfl_down(sz, o); ic += __shfl_down(ic, o);
    zmx = fmaxf(zmx, __shfl_down(zmx, o));
    zmn = fmaxf(zmn, __shfl_down(zmn, o));
  }
  if (lane == 0) { sD0[wid] = sz; sI0[wid] = ic; sF0[wid] = zmx; sF1[wid] = zmn; }
  __syncthreads();
  if (t == 0) {
    unsigned long long* e = zp + (size_t)b * 4;   // next-kernel consumer => plain stores
    e[0] = __double_as_longlong(sD0[0]+sD0[1]+sD0[2]+sD0[3]);
    e[1] = (unsigned long long)(sI0[0]+sI0[1]+sI0[2]+sI0[3]);
    float bmx = fmaxf(fmaxf(sF0[0], sF0[1]), fmaxf(sF0[2], sF0[3]));
    float bmn = fmaxf(fmaxf(sF1[0], sF1[1]), fmaxf(sF1[2], sF1[3]));
    e[2] = (unsigned long long)__float_as_uint(bmx) |
           ((unsigned long long)__float_as_uint(bmn) << 32);
  }
}

// ================= K6: final pmdg (1 block, plain loads) =================
__global__ __launch_bounds__(256) void k_final(float* __restrict__ out,
                                               char* __restrict__ ws) {
  const double* loss17p = (const double*)(ws + kOffL17);
  const unsigned long long* zp = (const unsigned long long*)(ws + kOffZP);

  const int t = threadIdx.x;
  const int lane = t & 63, wid = t >> 6;

  __shared__ double sD0[4];
  __shared__ int sI0[4];
  __shared__ float sF0[4], sF1[4];

  double gs = 0.0; int gi = 0; float gmx = -INFINITY, gmn = -INFINITY;
  for (int r = t; r < kB5; r += 256) {
    const unsigned long long* e = zp + (size_t)r * 4;
    gs += __longlong_as_double(e[0]);
    gi += (int)e[1];
    unsigned long long mm = e[2];
    gmx = fmaxf(gmx, __uint_as_float((unsigned)(mm & 0xFFFFFFFFu)));
    gmn = fmaxf(gmn, __uint_as_float((unsigned)(mm >> 32)));
  }
  for (int o = 32; o; o >>= 1) {
    gs += __shfl_down(gs, o); gi += __shfl_down(gi, o);
    gmx = fmaxf(gmx, __shfl_down(gmx, o));
    gmn = fmaxf(gmn, __shfl_down(gmn, o));
  }
  if (lane == 0) { sD0[wid] = gs; sI0[wid] = gi; sF0[wid] = gmx; sF1[wid] = gmn; }
  __syncthreads();
  if (t == 0) {
    double S = sD0[0]+sD0[1]+sD0[2]+sD0[3];
    int IC = sI0[0]+sI0[1]+sI0[2]+sI0[3];
    float MX = fmaxf(fmaxf(sF0[0], sF0[1]), fmaxf(sF0[2], sF0[3]));
    float MN = fmaxf(fmaxf(sF1[0], sF1[1]), fmaxf(sF1[2], sF1[3]));
    double below = 0.0, above = 0.0;
    if (IC > 0) {
      double icd = (double)IC;
      double mean = S / icd;
      below = (double)MX - mean;    // sum(|zc - zmax|)/icnt  (all zc <= zmax)
      above = mean - (double)(-MN); // sum(|zc - zmin|)/icnt
    }
    if (above == 0.0) above = 1e-7;
    double pmdg = 1000.0 * (above + below);
    out[4] = (float)pmdg;
    out[6] = (float)(*loss17p + pmdg);
  }
}

}  // namespace

extern "C" void kernel_launch(void* const* d_in, const int* in_sizes, int n_in,
                              void* d_out, int out_size, void* d_ws, size_t ws_size,
                              hipStream_t stream) {
  (void)in_sizes; (void)n_in; (void)out_size; (void)ws_size;
  const float* fake = (const float*)d_in[0];
  const float* real = (const float*)d_in[1];
  const int* epoch = (const int*)d_in[2];
  float* out = (float*)d_out;
  char* ws = (char*)d_ws;

  // host-computed distinct pointers so k_count's args are provably non-aliasing
  const float4* planes = (const float4*)(ws + kOffPlanes);
  const float4* pts    = (const float4*)(ws + kOffPts);
  unsigned* partial    = (unsigned*)(ws + kOffPartial);

  k_stats<<<kB1, 256, 0, stream>>>(fake, real, ws);
  k_mid<<<917, 256, 0, stream>>>(fake, out, ws);
  k_count<<<kB3, 256, 0, stream>>>(epoch, planes, pts, partial);
  k_select<<<16, 256, 0, stream>>>(ws);
  k_zc<<<kB5, 256, 0, stream>>>(epoch, ws);
  k_final<<<1, 256, 0, stream>>>(out, ws);
}

// Round 9
// 134.667 us; speedup vs baseline: 1.0093x; 1.0093x over previous
//
#include <hip/hip_runtime.h>

namespace {

typedef float v2f __attribute__((ext_vector_type(2)));

constexpr int kW = 640;
constexpr unsigned kSpan = 230400u;   // 360*640
constexpr int kB1 = 900;              // stats blocks (256 pts each)
constexpr int kB3 = 1024;             // count blocks (225 pts each, 128 thr x 8 planes)
constexpr int kPPB3 = 225;            // points per count block
constexpr int kB5 = 900;              // zc blocks (256 pts each)

// ws layout (bytes) — all handoffs are cross-kernel (stream-ordered), plain stores
constexpr size_t kOffMaxv    = 0;     // int, atomicMax accumulator of float bits
constexpr size_t kOffL17     = 8;     // f64 loss17
constexpr size_t kOffSel     = 16;    // u32 selkey (atomicMax in k_select)
constexpr size_t kOffPlanes  = 512;                      // 1024 * 16 = 16384
constexpr size_t kOffSP      = 512 + 16384;              // 900 * 48 = 43200
constexpr size_t kOffZP      = 61440;                    // 900 * 32 = 28800
constexpr size_t kOffPts     = 2097152;                  // pts: 230400*16 = 3.69 MB
constexpr size_t kOffPartial = 6291456;                  // 1024 * 128 * 8 = 1 MB

__device__ __forceinline__ unsigned rotl32(unsigned v, int r) {
  return (v << r) | (v >> (32 - r));
}

// Threefry-2x32, 20 rounds, key = (0, 42)  [jax.random.key(42)]
__device__ __forceinline__ void threefry(unsigned c0, unsigned c1,
                                         unsigned& o0, unsigned& o1) {
  const unsigned ks0 = 0u, ks1 = 42u, ks2 = 0x1BD11BDAu ^ 0u ^ 42u;
  unsigned x0 = c0 + ks0, x1 = c1 + ks1;
#define TFR(r) { x0 += x1; x1 = rotl32(x1, (r)); x1 ^= x0; }
  TFR(13) TFR(15) TFR(26) TFR(6)
  x0 += ks1; x1 += ks2 + 1u;
  TFR(17) TFR(29) TFR(16) TFR(24)
  x0 += ks2; x1 += ks0 + 2u;
  TFR(13) TFR(15) TFR(26) TFR(6)
  x0 += ks0; x1 += ks1 + 3u;
  TFR(17) TFR(29) TFR(16) TFR(24)
  x0 += ks1; x1 += ks2 + 4u;
  TFR(13) TFR(15) TFR(26) TFR(6)
  x0 += ks2; x1 += ks0 + 5u;
#undef TFR
  o0 = x0; o1 = x1;
}

__device__ __forceinline__ void pix_coords(float d, int row, int col, bool& valid,
                                           float& x, float& y, float& z) {
  valid = (d > 0.0f) && (d < 65535.0f);
  float z0 = d / 1000.0f;
  float x0 = z0 * ((float)col - 334.081f) / 460.585f;
  float y0 = z0 * ((float)row - 169.808f) / 460.268f;
  x = x0 * 1000.0f;
  y = y0 * 1000.0f;
  z = z0 * 1000.0f;
  if (x == 0.0f) x = 1e-7f;
  if (y == 0.0f) y = 1e-7f;
  if (z == 0.0f) z = 1e-7f;
}

// normalized point — identical expression wherever used (bitwise mask consistency)
__device__ __forceinline__ void make_pt(float d, int row, int col, float maxv,
                                        float& x, float& y, float& z) {
  bool v; float a, b, c;
  pix_coords(d, row, col, v, a, b, c);
  x = (v ? a : 0.f) / maxv;
  y = (v ? b : 0.f) / maxv;
  z = (v ? c : 0.f) / maxv;
}

__device__ __forceinline__ float get_thresh(int ep) {
  return (float)fmax(0.025 - 0.001 * (double)ep, 0.005);
}

// ===== K1: stats partials (plain stores) + raw pts + atomicMax maxv; ALL exit =====
__global__ __launch_bounds__(256) void k_stats(const float* __restrict__ fake,
                                               const float* __restrict__ real,
                                               char* __restrict__ ws) {
  int* maxvBits = (int*)(ws + kOffMaxv);
  double* sp = (double*)(ws + kOffSP);
  float4* ptsraw = (float4*)(ws + kOffPts);

  const int b = blockIdx.x, t = threadIdx.x;
  const int lane = t & 63, wid = t >> 6;

  __shared__ double sD0[4], sD1[4], sD2[4], sD3[4];
  __shared__ int sI0[4];
  __shared__ float sF0[4];

  int i = b * 256 + t;
  int row = i / kW, col = i - row * kW;
  bool vr, vf; float rx, ry, rz, fx, fy, fz;
  pix_coords(real[i], row, col, vr, rx, ry, rz);
  pix_coords(fake[i], row, col, vf, fx, fy, fz);
  // consumed only by later kernels (stream order) => plain store
  ptsraw[i] = make_float4(vf ? fx : 0.f, vf ? fy : 0.f, vf ? fz : 0.f, 0.f);
  double dx2 = 0, dy2 = 0, dz2 = 0, dl2 = 0; int cc = 0;
  if (vr && vf) {
    float ddx = rx - fx, ddy = ry - fy, ddz = rz - fz;
    dx2 = (double)ddx * (double)ddx;
    dy2 = (double)ddy * (double)ddy;
    dz2 = (double)ddz * (double)ddz;
    double dl = log(fabs((double)rz)) - log(fabs((double)fz));
    dl2 = dl * dl;
    cc = 1;
  }
  float mx = vf ? fmaxf(fmaxf(fx, fy), fz) : 0.0f;
  for (int o = 32; o; o >>= 1) {
    dx2 += __shfl_down(dx2, o); dy2 += __shfl_down(dy2, o);
    dz2 += __shfl_down(dz2, o); dl2 += __shfl_down(dl2, o);
    cc += __shfl_down(cc, o);
    mx = fmaxf(mx, __shfl_down(mx, o));
  }
  if (lane == 0) { sD0[wid]=dx2; sD1[wid]=dy2; sD2[wid]=dz2; sD3[wid]=dl2;
                   sI0[wid]=cc; sF0[wid]=mx; }
  __syncthreads();
  if (t == 0) {
    double* e = sp + (size_t)b * 6;
    e[0] = sD0[0]+sD0[1]+sD0[2]+sD0[3];
    e[1] = sD1[0]+sD1[1]+sD1[2]+sD1[3];
    e[2] = sD2[0]+sD2[1]+sD2[2]+sD2[3];
    e[3] = sD3[0]+sD3[1]+sD3[2]+sD3[3];
    e[4] = (double)(sI0[0]+sI0[1]+sI0[2]+sI0[3]);
    float bm = fmaxf(fmaxf(sF0[0], sF0[1]), fmaxf(sF0[2], sF0[3]));
    // non-negative float bits as signed int: max is order-independent;
    // ws poison 0xAAAAAAAA is negative as signed => any candidate wins.
    atomicMax(maxvBits, (int)__float_as_uint(bm));
  }
}

// ===== K2: blocks 0..15 = planes (3-way gather split, 64 planes/block);
//           block 16 = f64 scalar reduce + out[0..3,5];
//           blocks 17..916 = normalize pts IN-PLACE (raw/maxv, division once) =====
__global__ __launch_bounds__(256) void k_mid(const float* __restrict__ fake,
                                             float* __restrict__ out,
                                             char* __restrict__ ws) {
  const int* maxvBits = (const int*)(ws + kOffMaxv);
  double* loss17p = (double*)(ws + kOffL17);
  unsigned* selkeyp = (unsigned*)(ws + kOffSel);
  float4* planes = (float4*)(ws + kOffPlanes);
  const double* sp = (const double*)(ws + kOffSP);
  float4* pts = (float4*)(ws + kOffPts);

  const int t = threadIdx.x;
  const int lane = t & 63, wid = t >> 6;

  if (blockIdx.x >= 17) {
    // ---- normalize in place: each thread owns one element (no races);
    //      consumers are later kernels only. Same division expression as before. ----
    const float maxv = __uint_as_float((unsigned)*maxvBits);
    int i = (blockIdx.x - 17) * 256 + t;
    float4 r = pts[i];
    pts[i] = make_float4(r.x / maxv, r.y / maxv, r.z / maxv, 0.f);
  } else if (blockIdx.x == 16) {
    // ---- scalar reduce: identical accumulation order to the proven version ----
    __shared__ double sD0[4], sD1[4], sD2[4], sD3[4];
    __shared__ int sI0[4];
    double gx = 0, gy = 0, gz = 0, gl = 0; int gc = 0;
    for (int r = t; r < kB1; r += 256) {
      const double* e = sp + (size_t)r * 6;
      gx += e[0]; gy += e[1]; gz += e[2]; gl += e[3];
      gc += (int)e[4];
    }
    for (int o = 32; o; o >>= 1) {
      gx += __shfl_down(gx, o); gy += __shfl_down(gy, o);
      gz += __shfl_down(gz, o); gl += __shfl_down(gl, o);
      gc += __shfl_down(gc, o);
    }
    if (lane == 0) { sD0[wid]=gx; sD1[wid]=gy; sD2[wid]=gz; sD3[wid]=gl; sI0[wid]=gc; }
    __syncthreads();
    if (t == 0) {
      double SX = sD0[0]+sD0[1]+sD0[2]+sD0[3];
      double SY = sD1[0]+sD1[1]+sD1[2]+sD1[3];
      double SZ = sD2[0]+sD2[1]+sD2[2]+sD2[3];
      double SL = sD3[0]+sD3[1]+sD3[2]+sD3[3];
      int CN = sI0[0]+sI0[1]+sI0[2]+sI0[3];
      double cntd = (CN > 0) ? (double)CN : 1.0;
      double lossX = sqrt(SX / cntd);
      double lossY = sqrt(SY / cntd);
      double lossZ = sqrt(SZ / cntd);
      double rmse_log = 10000.0 * sqrt(SL / cntd);
      double loss17 = rmse_log * fabs(10.0 * (3.0 - exp(lossX) - exp(lossY) - exp(lossZ)));
      *loss17p = loss17;
      *selkeyp = 0u;                  // atomicMax target for k_select
      out[0] = (float)rmse_log;
      out[1] = (float)lossX;
      out[2] = (float)lossY;
      out[3] = (float)lossZ;
      out[5] = (float)loss17;
    }
  } else {
    // ---- planes: 64 per block; 192 gather threads (one (pid,v) each) ----
    const float maxv = __uint_as_float((unsigned)*maxvBits);
    __shared__ float sX[192], sY[192], sZ[192];
    if (t < 192) {
      int j = t / 3;                        // 0..63 local plane
      int v = t - j * 3;                    // 0..2 vertex
      int pid = blockIdx.x * 64 + j;        // 0..1023
      if (pid < 1000) {
        unsigned p = 3u * (unsigned)pid + (unsigned)v;
        unsigned o0, o1;
        threefry(p, p + 3000u, o0, o1);     // JAX randint: o1 % span
        unsigned idx = o1 % kSpan;
        int row = (int)(idx / kW), col = (int)idx - row * kW;
        float x, y, z;
        make_pt(fake[idx], row, col, maxv, x, y, z);
        sX[t] = x; sY[t] = y; sZ[t] = z;
      }
    }
    __syncthreads();
    if (t < 64) {
      int pid = blockIdx.x * 64 + t;
      if (pid < 1000) {
        float px[3], py[3], pz[3];
#pragma unroll
        for (int v = 0; v < 3; v++) {
          px[v] = sX[3 * t + v]; py[v] = sY[3 * t + v]; pz[v] = sZ[3 * t + v];
        }
        float ax = px[1]-px[0], ay = py[1]-py[0], az = pz[1]-pz[0];
        float bx = px[2]-px[0], by = py[2]-py[0], bz = pz[2]-pz[0];
        float nx = ay*bz - az*by;
        float ny = az*bx - ax*bz;
        float nz = ax*by - ay*bx;
        float nn = sqrtf(nx*nx + ny*ny + nz*nz);
        nx /= nn; ny /= nn; nz /= nn;
        float kk = -(nx*px[1] + ny*py[1] + nz*pz[1]);
        planes[pid] = make_float4(nx, ny, nz, kk);   // next-kernel consumer => plain
      } else {
        planes[pid] = make_float4(0.f, 0.f, 0.f, 3e38f);  // dummy: never an inlier
      }
    }
  }
}

// ===== K3: count; 1024 blocks x 128 threads, 8 planes/thread (4 v2f pairs),
//           NO LDS, wave-uniform point loads; per-point cost amortized over 8 tests =====
__global__ __launch_bounds__(128) void k_count(const int* __restrict__ epoch,
                                               const float4* __restrict__ planes,
                                               const float4* __restrict__ pts,
                                               uint2* __restrict__ partial) {
  const int b = blockIdx.x, t = threadIdx.x;
  const float th = get_thresh(*epoch);

  // thread owns planes t*8 .. t*8+7 as 4 v2f pairs
  float4 p0 = planes[t * 8 + 0], p1 = planes[t * 8 + 1];
  float4 p2 = planes[t * 8 + 2], p3 = planes[t * 8 + 3];
  float4 p4 = planes[t * 8 + 4], p5 = planes[t * 8 + 5];
  float4 p6 = planes[t * 8 + 6], p7 = planes[t * 8 + 7];
  v2f Ax = {p0.x, p1.x}, Ay = {p0.y, p1.y}, Az = {p0.z, p1.z}, Aw = {p0.w, p1.w};
  v2f Bx = {p2.x, p3.x}, By = {p2.y, p3.y}, Bz = {p2.z, p3.z}, Bw = {p2.w, p3.w};
  v2f Cx = {p4.x, p5.x}, Cy = {p4.y, p5.y}, Cz = {p4.z, p5.z}, Cw = {p4.w, p5.w};
  v2f Dx = {p6.x, p7.x}, Dy = {p6.y, p7.y}, Dz = {p6.z, p7.z}, Dw = {p6.w, p7.w};

  const float4* __restrict__ base = pts + b * kPPB3;

  int c0 = 0, c1 = 0, c2 = 0, c3 = 0, c4 = 0, c5 = 0, c6 = 0, c7 = 0;
#pragma unroll 5
  for (int s = 0; s < kPPB3; ++s) {
    float4 q = base[s];                    // wave-uniform address -> scalar/broadcast load
    v2f qx = {q.x, q.x}, qy = {q.y, q.y}, qz = {q.z, q.z};
    // per-half chain == fmaf(qx, a, fmaf(qy, b, fmaf(qz, c, d))) — matches k_zc
    v2f dA = __builtin_elementwise_fma(qx, Ax,
             __builtin_elementwise_fma(qy, Ay,
             __builtin_elementwise_fma(qz, Az, Aw)));
    v2f dB = __builtin_elementwise_fma(qx, Bx,
             __builtin_elementwise_fma(qy, By,
             __builtin_elementwise_fma(qz, Bz, Bw)));
    v2f dC = __builtin_elementwise_fma(qx, Cx,
             __builtin_elementwise_fma(qy, Cy,
             __builtin_elementwise_fma(qz, Cz, Cw)));
    v2f dD = __builtin_elementwise_fma(qx, Dx,
             __builtin_elementwise_fma(qy, Dy,
             __builtin_elementwise_fma(qz, Dz, Dw)));
    c0 += (fabsf(dA.x) <= th) ? 1 : 0;
    c1 += (fabsf(dA.y) <= th) ? 1 : 0;
    c2 += (fabsf(dB.x) <= th) ? 1 : 0;
    c3 += (fabsf(dB.y) <= th) ? 1 : 0;
    c4 += (fabsf(dC.x) <= th) ? 1 : 0;
    c5 += (fabsf(dC.y) <= th) ? 1 : 0;
    c6 += (fabsf(dD.x) <= th) ? 1 : 0;
    c7 += (fabsf(dD.y) <= th) ? 1 : 0;
  }
  // counts <= 225 fit u8; 8 counts pack into one uint2 store
  partial[b * 128 + t] = make_uint2(
      (unsigned)c0 | ((unsigned)c1 << 8) | ((unsigned)c2 << 16) | ((unsigned)c3 << 24),
      (unsigned)c4 | ((unsigned)c5 << 8) | ((unsigned)c6 << 16) | ((unsigned)c7 << 24));
}

// ===== K4: select over 8-planes/thread partials (16 blocks x 64 planes) =====
__global__ __launch_bounds__(256) void k_select(char* __restrict__ ws) {
  unsigned* selkeyp = (unsigned*)(ws + kOffSel);
  const unsigned* partial = (const unsigned*)(ws + kOffPartial);  // as u32 words

  const int r = blockIdx.x;             // 0..15: planes r*64 .. r*64+63
  const int t = threadIdx.x;

  __shared__ unsigned sAcc[64][5];      // padded: conflict-light

  int l = t & 63;                       // local plane
  int chunk = t >> 6;                   // 0..3: 256 point-blocks each
  int p = r * 64 + l;
  int to = p >> 3;                      // owner thread 0..127
  int w = (p & 7) >> 2;                 // u32 word within uint2
  int byt = p & 3;                      // byte within word
  unsigned cnt = 0;
  for (int pb = chunk * 256; pb < chunk * 256 + 256; ++pb) {
    unsigned v = partial[(pb * 128 + to) * 2 + w];
    cnt += (v >> (8 * byt)) & 0xFFu;
  }
  sAcc[l][chunk] = cnt;
  __syncthreads();

  unsigned mykey = 0u;
  if (t < 64) {                         // wave 0 finalizes
    unsigned tot = sAcc[t][0] + sAcc[t][1] + sAcc[t][2] + sAcc[t][3];
    int p2 = r * 64 + t;
    if (p2 < 1000) {
      int score = ((int)tot > 5000) ? (int)tot : -1;   // MIN_POINTS, strict >
      mykey = ((unsigned)(score + 2) << 10) | (unsigned)(1023 - p2);
    }
  }
  for (int o = 32; o; o >>= 1) {
    unsigned other = __shfl_down(mykey, o);
    mykey = other > mykey ? other : mykey;
  }
  if (t == 0) atomicMax(selkeyp, mykey);
}

// ===== K5: zc partials over best plane's inliers (pre-normalized pts); ALL exit =====
__global__ __launch_bounds__(256) void k_zc(const int* __restrict__ epoch,
                                            char* __restrict__ ws) {
  const float4* planes = (const float4*)(ws + kOffPlanes);
  unsigned long long* zp = (unsigned long long*)(ws + kOffZP);
  const float4* pts = (const float4*)(ws + kOffPts);

  const int b = blockIdx.x, t = threadIdx.x;
  const int lane = t & 63, wid = t >> 6;
  const float th = get_thresh(*epoch);

  // best plane + rotation derived per block (cheap, uniform; cross-kernel plain loads)
  unsigned selkey = *(const unsigned*)(ws + kOffSel);
  int best = 1023 - (int)(selkey & 1023u);
  float4 pl = planes[best];
  const float a = pl.x, bb = pl.y, c = pl.z, d = pl.w;
  float n2 = a * a + bb * bb + c * c;
  float cos_t = c / sqrtf(n2);
  float sin_t = sqrtf((a * a + bb * bb) / n2);
  float sab = sqrtf(a * a + bb * bb);
  float u1 = bb / sab, u2 = -a / sab;
  const float r0 = -u2 * sin_t, r1 = u1 * sin_t, r2 = cos_t, tz = d / c;

  __shared__ double sD0[4];
  __shared__ int sI0[4];
  __shared__ float sF0[4], sF1[4];

  double sz = 0.0; int ic = 0; float zmx = -INFINITY, zmn = -INFINITY;  // zmn = max(-zc)
  {
    float4 q = pts[b * 256 + t];   // already normalized (same bits as before)
    // identical per-lane chain to k_count's pk_fma halves
    float dist = fmaf(q.x, a, fmaf(q.y, bb, fmaf(q.z, c, d)));
    if (fabsf(dist) <= th) {
      float zc = fmaf(q.x, r0, fmaf(q.y, r1, (q.z + tz) * r2));
      sz = (double)zc; ic = 1; zmx = zc; zmn = -zc;
    }
  }
  for (int o = 32; o; o >>= 1) {
    sz += __shfl_down(sz, o); ic += __shfl_down(ic, o);
    zmx = fmaxf(zmx, __shfl_down(zmx, o));
    zmn = fmaxf(zmn, __shfl_down(zmn, o));
  }
  if (lane == 0) { sD0[wid] = sz; sI0[wid] = ic; sF0[wid] = zmx; sF1[wid] = zmn; }
  __syncthreads();
  if (t == 0) {
    unsigned long long* e = zp + (size_t)b * 4;   // next-kernel consumer => plain stores
    e[0] = __double_as_longlong(sD0[0]+sD0[1]+sD0[2]+sD0[3]);
    e[1] = (unsigned long long)(sI0[0]+sI0[1]+sI0[2]+sI0[3]);
    float bmx = fmaxf(fmaxf(sF0[0], sF0[1]), fmaxf(sF0[2], sF0[3]));
    float bmn = fmaxf(fmaxf(sF1[0], sF1[1]), fmaxf(sF1[2], sF1[3]));
    e[2] = (unsigned long long)__float_as_uint(bmx) |
           ((unsigned long long)__float_as_uint(bmn) << 32);
  }
}

// ================= K6: final pmdg (1 block, plain loads) =================
__global__ __launch_bounds__(256) void k_final(float* __restrict__ out,
                                               char* __restrict__ ws) {
  const double* loss17p = (const double*)(ws + kOffL17);
  const unsigned long long* zp = (const unsigned long long*)(ws + kOffZP);

  const int t = threadIdx.x;
  const int lane = t & 63, wid = t >> 6;

  __shared__ double sD0[4];
  __shared__ int sI0[4];
  __shared__ float sF0[4], sF1[4];

  double gs = 0.0; int gi = 0; float gmx = -INFINITY, gmn = -INFINITY;
  for (int r = t; r < kB5; r += 256) {
    const unsigned long long* e = zp + (size_t)r * 4;
    gs += __longlong_as_double(e[0]);
    gi += (int)e[1];
    unsigned long long mm = e[2];
    gmx = fmaxf(gmx, __uint_as_float((unsigned)(mm & 0xFFFFFFFFu)));
    gmn = fmaxf(gmn, __uint_as_float((unsigned)(mm >> 32)));
  }
  for (int o = 32; o; o >>= 1) {
    gs += __shfl_down(gs, o); gi += __shfl_down(gi, o);
    gmx = fmaxf(gmx, __shfl_down(gmx, o));
    gmn = fmaxf(gmn, __shfl_down(gmn, o));
  }
  if (lane == 0) { sD0[wid] = gs; sI0[wid] = gi; sF0[wid] = gmx; sF1[wid] = gmn; }
  __syncthreads();
  if (t == 0) {
    double S = sD0[0]+sD0[1]+sD0[2]+sD0[3];
    int IC = sI0[0]+sI0[1]+sI0[2]+sI0[3];
    float MX = fmaxf(fmaxf(sF0[0], sF0[1]), fmaxf(sF0[2], sF0[3]));
    float MN = fmaxf(fmaxf(sF1[0], sF1[1]), fmaxf(sF1[2], sF1[3]));
    double below = 0.0, above = 0.0;
    if (IC > 0) {
      double icd = (double)IC;
      double mean = S / icd;
      below = (double)MX - mean;    // sum(|zc - zmax|)/icnt  (all zc <= zmax)
      above = mean - (double)(-MN); // sum(|zc - zmin|)/icnt
    }
    if (above == 0.0) above = 1e-7;
    double pmdg = 1000.0 * (above + below);
    out[4] = (float)pmdg;
    out[6] = (float)(*loss17p + pmdg);
  }
}

}  // namespace

extern "C" void kernel_launch(void* const* d_in, const int* in_sizes, int n_in,
                              void* d_out, int out_size, void* d_ws, size_t ws_size,
                              hipStream_t stream) {
  (void)in_sizes; (void)n_in; (void)out_size; (void)ws_size;
  const float* fake = (const float*)d_in[0];
  const float* real = (const float*)d_in[1];
  const int* epoch = (const int*)d_in[2];
  float* out = (float*)d_out;
  char* ws = (char*)d_ws;

  // host-computed distinct pointers so k_count's args are provably non-aliasing
  const float4* planes = (const float4*)(ws + kOffPlanes);
  const float4* pts    = (const float4*)(ws + kOffPts);
  uint2* partial       = (uint2*)(ws + kOffPartial);

  k_stats<<<kB1, 256, 0, stream>>>(fake, real, ws);
  k_mid<<<917, 256, 0, stream>>>(fake, out, ws);
  k_count<<<kB3, 128, 0, stream>>>(epoch, planes, pts, partial);
  k_select<<<16, 256, 0, stream>>>(ws);
  k_zc<<<kB5, 256, 0, stream>>>(epoch, ws);
  k_final<<<1, 256, 0, stream>>>(out, ws);
}

// Round 10
// 118.693 us; speedup vs baseline: 1.1451x; 1.1346x over previous
//
#include <hip/hip_runtime.h>

namespace {

typedef float v2f __attribute__((ext_vector_type(2)));

constexpr int kW = 640;
constexpr unsigned kSpan = 230400u;   // 360*640
constexpr int kB1 = 900;              // stats blocks (256 pts each)
constexpr int kB3 = 1024;             // count blocks (225 pts each)
constexpr int kPPB3 = 225;            // points per count block
constexpr int kB5 = 900;              // zc blocks (256 pts each)

// ws layout (bytes) — all handoffs are cross-kernel (stream-ordered), plain stores
constexpr size_t kOffAcc     = 0;       // +0 maxvBits (int, atomicMax), +8 loss17 (f64), +16 selkey (u32)
constexpr size_t kOffPlanes  = 512;                                  // 1024 * 16 = 16384
constexpr size_t kOffSP      = 512 + 16384;                          // 900 * 6 * 8 = 43200
constexpr size_t kOffZP      = kOffSP + 43200;                       // 900 * 2 * 8 = 14400
constexpr size_t kOffZM      = kOffZP + 14400;                       // 900 * 8 = 7200
constexpr size_t kOffPartial = 81920;                                // 1024 * 256 * 4 = 1 MB
constexpr size_t kOffPts     = kOffPartial + (size_t)kB3 * 256 * 4;  // 230400*16 = 3.69 MB
// total ~4.8 MB

__device__ __forceinline__ unsigned rotl32(unsigned v, int r) {
  return (v << r) | (v >> (32 - r));
}

// Threefry-2x32, 20 rounds, key = (0, 42)  [jax.random.key(42)]
__device__ __forceinline__ void threefry(unsigned c0, unsigned c1,
                                         unsigned& o0, unsigned& o1) {
  const unsigned ks0 = 0u, ks1 = 42u, ks2 = 0x1BD11BDAu ^ 0u ^ 42u;
  unsigned x0 = c0 + ks0, x1 = c1 + ks1;
#define TFR(r) { x0 += x1; x1 = rotl32(x1, (r)); x1 ^= x0; }
  TFR(13) TFR(15) TFR(26) TFR(6)
  x0 += ks1; x1 += ks2 + 1u;
  TFR(17) TFR(29) TFR(16) TFR(24)
  x0 += ks2; x1 += ks0 + 2u;
  TFR(13) TFR(15) TFR(26) TFR(6)
  x0 += ks0; x1 += ks1 + 3u;
  TFR(17) TFR(29) TFR(16) TFR(24)
  x0 += ks1; x1 += ks2 + 4u;
  TFR(13) TFR(15) TFR(26) TFR(6)
  x0 += ks2; x1 += ks0 + 5u;
#undef TFR
  o0 = x0; o1 = x1;
}

__device__ __forceinline__ void pix_coords(float d, int row, int col, bool& valid,
                                           float& x, float& y, float& z) {
  valid = (d > 0.0f) && (d < 65535.0f);
  float z0 = d / 1000.0f;
  float x0 = z0 * ((float)col - 334.081f) / 460.585f;
  float y0 = z0 * ((float)row - 169.808f) / 460.268f;
  x = x0 * 1000.0f;
  y = y0 * 1000.0f;
  z = z0 * 1000.0f;
  if (x == 0.0f) x = 1e-7f;
  if (y == 0.0f) y = 1e-7f;
  if (z == 0.0f) z = 1e-7f;
}

// normalized point — identical expression wherever used (bitwise mask consistency)
__device__ __forceinline__ void make_pt(float d, int row, int col, float maxv,
                                        float& x, float& y, float& z) {
  bool v; float a, b, c;
  pix_coords(d, row, col, v, a, b, c);
  x = (v ? a : 0.f) / maxv;
  y = (v ? b : 0.f) / maxv;
  z = (v ? c : 0.f) / maxv;
}

__device__ __forceinline__ float get_thresh(int ep) {
  return (float)fmax(0.025 - 0.001 * (double)ep, 0.005);
}

// ================= K1: stats partials + raw pts + global maxv; ALL blocks exit =================
__global__ __launch_bounds__(256) void k_stats(const float* __restrict__ fake,
                                               const float* __restrict__ real,
                                               char* __restrict__ ws) {
  int* maxvBits = (int*)(ws + kOffAcc);
  double* sp = (double*)(ws + kOffSP);
  float4* ptsraw = (float4*)(ws + kOffPts);

  const int b = blockIdx.x, t = threadIdx.x;
  const int lane = t & 63, wid = t >> 6;

  __shared__ double sD0[4], sD1[4], sD2[4], sD3[4];
  __shared__ int sI0[4];
  __shared__ float sF0[4];

  int i = b * 256 + t;
  int row = i / kW, col = i - row * kW;
  bool vr, vf; float rx, ry, rz, fx, fy, fz;
  pix_coords(real[i], row, col, vr, rx, ry, rz);
  pix_coords(fake[i], row, col, vf, fx, fy, fz);
  // raw (unnormalized, mask-applied) point — consumed by later kernels (stream order)
  ptsraw[i] = make_float4(vf ? fx : 0.f, vf ? fy : 0.f, vf ? fz : 0.f, 0.f);
  double dx2 = 0, dy2 = 0, dz2 = 0, dl2 = 0; int cc = 0;
  if (vr && vf) {
    float ddx = rx - fx, ddy = ry - fy, ddz = rz - fz;
    dx2 = (double)ddx * (double)ddx;
    dy2 = (double)ddy * (double)ddy;
    dz2 = (double)ddz * (double)ddz;
    double dl = log(fabs((double)rz)) - log(fabs((double)fz));
    dl2 = dl * dl;
    cc = 1;
  }
  float mx = vf ? fmaxf(fmaxf(fx, fy), fz) : 0.0f;
  for (int o = 32; o; o >>= 1) {
    dx2 += __shfl_down(dx2, o); dy2 += __shfl_down(dy2, o);
    dz2 += __shfl_down(dz2, o); dl2 += __shfl_down(dl2, o);
    cc += __shfl_down(cc, o);
    mx = fmaxf(mx, __shfl_down(mx, o));
  }
  if (lane == 0) { sD0[wid]=dx2; sD1[wid]=dy2; sD2[wid]=dz2; sD3[wid]=dl2;
                   sI0[wid]=cc; sF0[wid]=mx; }
  __syncthreads();
  if (t == 0) {
    double* e = sp + (size_t)b * 6;
    e[0] = sD0[0]+sD0[1]+sD0[2]+sD0[3];
    e[1] = sD1[0]+sD1[1]+sD1[2]+sD1[3];
    e[2] = sD2[0]+sD2[1]+sD2[2]+sD2[3];
    e[3] = sD3[0]+sD3[1]+sD3[2]+sD3[3];
    e[4] = (double)(sI0[0]+sI0[1]+sI0[2]+sI0[3]);
    float bm = fmaxf(fmaxf(sF0[0], sF0[1]), fmaxf(sF0[2], sF0[3]));
    // all candidates are non-negative float bits => positive signed ints;
    // ws poison 0xAAAAAAAA is negative as signed => any candidate beats it.
    // max is order-independent => bit-identical to the old fmax tree.
    atomicMax(maxvBits, (int)__float_as_uint(bm));
  }
}

// ========== K2: block 4 = global stats reduce + scalars; blocks 0..3 = 256 planes each ==========
__global__ __launch_bounds__(256) void k_scalars_planes(const float* __restrict__ fake,
                                                        float* __restrict__ out,
                                                        char* __restrict__ ws) {
  const int* maxvBits = (const int*)(ws + kOffAcc);
  double* loss17p = (double*)(ws + kOffAcc + 8);
  unsigned* selkeyp = (unsigned*)(ws + kOffAcc + 16);
  float4* planes = (float4*)(ws + kOffPlanes);
  const double* sp = (const double*)(ws + kOffSP);

  const int t = threadIdx.x;
  const int lane = t & 63, wid = t >> 6;

  if (blockIdx.x == 4) {
    // ---- global stats reduce (identical accumulation order to the proven tail) ----
    __shared__ double sD0[4], sD1[4], sD2[4], sD3[4];
    __shared__ int sI0[4];
    double gx = 0, gy = 0, gz = 0, gl = 0; int gc = 0;
    for (int r = t; r < kB1; r += 256) {
      const double* e = sp + (size_t)r * 6;
      gx += e[0]; gy += e[1]; gz += e[2]; gl += e[3];
      gc += (int)e[4];
    }
    for (int o = 32; o; o >>= 1) {
      gx += __shfl_down(gx, o); gy += __shfl_down(gy, o);
      gz += __shfl_down(gz, o); gl += __shfl_down(gl, o);
      gc += __shfl_down(gc, o);
    }
    if (lane == 0) { sD0[wid]=gx; sD1[wid]=gy; sD2[wid]=gz; sD3[wid]=gl; sI0[wid]=gc; }
    __syncthreads();
    if (t == 0) {
      double SX = sD0[0]+sD0[1]+sD0[2]+sD0[3];
      double SY = sD1[0]+sD1[1]+sD1[2]+sD1[3];
      double SZ = sD2[0]+sD2[1]+sD2[2]+sD2[3];
      double SL = sD3[0]+sD3[1]+sD3[2]+sD3[3];
      int CN = sI0[0]+sI0[1]+sI0[2]+sI0[3];
      double cntd = (CN > 0) ? (double)CN : 1.0;
      double lossX = sqrt(SX / cntd);
      double lossY = sqrt(SY / cntd);
      double lossZ = sqrt(SZ / cntd);
      double rmse_log = 10000.0 * sqrt(SL / cntd);
      double loss17 = rmse_log * fabs(10.0 * (3.0 - exp(lossX) - exp(lossY) - exp(lossZ)));
      *loss17p = loss17;
      *selkeyp = 0u;                  // atomicMax target for k_select
      out[0] = (float)rmse_log;
      out[1] = (float)lossX;
      out[2] = (float)lossY;
      out[3] = (float)lossZ;
      out[5] = (float)loss17;
    }
  } else {
    // ---- plane build: blocks 0..3, one plane per thread (pid 0..1023) ----
    const float maxv = __uint_as_float((unsigned)*maxvBits);
    int pid = blockIdx.x * 256 + t;
    if (pid < 1000) {
      float px[3], py[3], pz[3];
#pragma unroll
      for (int v = 0; v < 3; v++) {
        unsigned p = 3u * (unsigned)pid + (unsigned)v;
        unsigned o0, o1;
        threefry(p, p + 3000u, o0, o1);  // JAX randint: o1 % span
        unsigned idx = o1 % kSpan;
        int row = (int)(idx / kW), col = (int)idx - row * kW;
        make_pt(fake[idx], row, col, maxv, px[v], py[v], pz[v]);
      }
      float ax = px[1]-px[0], ay = py[1]-py[0], az = pz[1]-pz[0];
      float bx = px[2]-px[0], by = py[2]-py[0], bz = pz[2]-pz[0];
      float nx = ay*bz - az*by;
      float ny = az*bx - ax*bz;
      float nz = ax*by - ay*bx;
      float nn = sqrtf(nx*nx + ny*ny + nz*nz);
      nx /= nn; ny /= nn; nz /= nn;
      float kk = -(nx*px[1] + ny*py[1] + nz*pz[1]);
      planes[pid] = make_float4(nx, ny, nz, kk);
    } else {
      planes[pid] = make_float4(0.f, 0.f, 0.f, 3e38f);  // dummy: never an inlier
    }
  }
}

// ===== K3: planes-in-VGPR count; 2-point ILP (4 independent fma chains); ALL exit =====
__global__ __launch_bounds__(256) void k_count(const int* __restrict__ epoch,
                                               char* __restrict__ ws) {
  const int* maxvBits = (const int*)(ws + kOffAcc);
  const float4* planes = (const float4*)(ws + kOffPlanes);
  unsigned* partial = (unsigned*)(ws + kOffPartial);
  const float4* ptsraw = (const float4*)(ws + kOffPts);

  const int b = blockIdx.x, t = threadIdx.x;
  const float th = get_thresh(*epoch);
  const float maxv = __uint_as_float((unsigned)*maxvBits);

  __shared__ float4 sPts[kPPB3];

  // stage this block's 225 points, normalized (identical expression to k_zc)
  if (t < kPPB3) {
    float4 r = ptsraw[b * kPPB3 + t];
    sPts[t] = make_float4(r.x / maxv, r.y / maxv, r.z / maxv, 0.f);
  }
  // each lane owns 4 planes in registers (pairs for pk_fma)
  float4 p0 = planes[t * 4 + 0], p1 = planes[t * 4 + 1];
  float4 p2 = planes[t * 4 + 2], p3 = planes[t * 4 + 3];
  v2f Ax = {p0.x, p1.x}, Ay = {p0.y, p1.y}, Az = {p0.z, p1.z}, Aw = {p0.w, p1.w};
  v2f Bx = {p2.x, p3.x}, By = {p2.y, p3.y}, Bz = {p2.z, p3.z}, Bw = {p2.w, p3.w};
  __syncthreads();

  int c0 = 0, c1 = 0, c2 = 0, c3 = 0;
  // 2 points per iteration -> 4 independent 3-deep pk_fma chains (latency hiding).
  // Same per-point expressions as before; integer sums commute => identical counts.
#pragma unroll 4
  for (int s = 0; s < kPPB3 - 1; s += 2) {
    float4 q0 = sPts[s];
    float4 q1 = sPts[s + 1];
    v2f q0x = {q0.x, q0.x}, q0y = {q0.y, q0.y}, q0z = {q0.z, q0.z};
    v2f q1x = {q1.x, q1.x}, q1y = {q1.y, q1.y}, q1z = {q1.z, q1.z};
    v2f dA0 = __builtin_elementwise_fma(q0x, Ax,
              __builtin_elementwise_fma(q0y, Ay,
              __builtin_elementwise_fma(q0z, Az, Aw)));
    v2f dB0 = __builtin_elementwise_fma(q0x, Bx,
              __builtin_elementwise_fma(q0y, By,
              __builtin_elementwise_fma(q0z, Bz, Bw)));
    v2f dA1 = __builtin_elementwise_fma(q1x, Ax,
              __builtin_elementwise_fma(q1y, Ay,
              __builtin_elementwise_fma(q1z, Az, Aw)));
    v2f dB1 = __builtin_elementwise_fma(q1x, Bx,
              __builtin_elementwise_fma(q1y, By,
              __builtin_elementwise_fma(q1z, Bz, Bw)));
    c0 += ((fabsf(dA0.x) <= th) ? 1 : 0) + ((fabsf(dA1.x) <= th) ? 1 : 0);
    c1 += ((fabsf(dA0.y) <= th) ? 1 : 0) + ((fabsf(dA1.y) <= th) ? 1 : 0);
    c2 += ((fabsf(dB0.x) <= th) ? 1 : 0) + ((fabsf(dB1.x) <= th) ? 1 : 0);
    c3 += ((fabsf(dB0.y) <= th) ? 1 : 0) + ((fabsf(dB1.y) <= th) ? 1 : 0);
  }
  {  // tail point s = 224
    float4 q = sPts[kPPB3 - 1];
    v2f qx = {q.x, q.x}, qy = {q.y, q.y}, qz = {q.z, q.z};
    v2f dA = __builtin_elementwise_fma(qx, Ax,
             __builtin_elementwise_fma(qy, Ay,
             __builtin_elementwise_fma(qz, Az, Aw)));
    v2f dB = __builtin_elementwise_fma(qx, Bx,
             __builtin_elementwise_fma(qy, By,
             __builtin_elementwise_fma(qz, Bz, Bw)));
    c0 += (fabsf(dA.x) <= th) ? 1 : 0;
    c1 += (fabsf(dA.y) <= th) ? 1 : 0;
    c2 += (fabsf(dB.x) <= th) ? 1 : 0;
    c3 += (fabsf(dB.y) <= th) ? 1 : 0;
  }
  // counts <= 225 fit u8; one packed store per thread
  partial[b * 256 + t] =
      (unsigned)c0 | ((unsigned)c1 << 8) | ((unsigned)c2 << 16) | ((unsigned)c3 << 24);
}

// ================= K4: two-stage select over partials (16 blocks) =================
__global__ __launch_bounds__(256) void k_select(char* __restrict__ ws) {
  unsigned* selkeyp = (unsigned*)(ws + kOffAcc + 16);
  const unsigned* partial = (const unsigned*)(ws + kOffPartial);

  const int r = blockIdx.x;             // 0..15: owns owner-threads r*16..r*16+15 (64 planes)
  const int t = threadIdx.x;

  __shared__ uint4 sAcc[16][16];

  int owner = r * 16 + (t & 15);        // global owner-thread index 0..255
  int chunk = t >> 4;                   // 16 row-chunks of 64 rows
  unsigned s0 = 0, s1 = 0, s2 = 0, s3 = 0;
  for (int row = chunk * 64; row < chunk * 64 + 64; ++row) {
    unsigned v = partial[row * 256 + owner];
    s0 += v & 0xFFu; s1 += (v >> 8) & 0xFFu;
    s2 += (v >> 16) & 0xFFu; s3 += (v >> 24) & 0xFFu;
  }
  sAcc[t & 15][chunk] = make_uint4(s0, s1, s2, s3);
  __syncthreads();

  unsigned mykey = 0u;
  if (t < 16) {
    unsigned t0 = 0, t1 = 0, t2 = 0, t3 = 0;
    for (int j = 0; j < 16; ++j) {
      uint4 v = sAcc[t][j];
      t0 += v.x; t1 += v.y; t2 += v.z; t3 += v.w;
    }
    unsigned tot[4] = {t0, t1, t2, t3};
    int pbase = (r * 16 + t) * 4;
#pragma unroll
    for (int k = 0; k < 4; ++k) {
      int p = pbase + k;
      if (p < 1000) {
        int score = ((int)tot[k] > 5000) ? (int)tot[k] : -1;   // MIN_POINTS, strict >
        unsigned key = ((unsigned)(score + 2) << 10) | (unsigned)(1023 - p);
        mykey = key > mykey ? key : mykey;
      }
    }
  }
  for (int o = 32; o; o >>= 1) {
    unsigned other = __shfl_down(mykey, o);
    mykey = other > mykey ? other : mykey;
  }
  if (t == 0) atomicMax(selkeyp, mykey);
}

// ================= K5: zc partials over best plane's inliers; ALL blocks exit =================
__global__ __launch_bounds__(256) void k_zc(const int* __restrict__ epoch,
                                            char* __restrict__ ws) {
  const int* maxvBits = (const int*)(ws + kOffAcc);
  const unsigned* selkeyp = (const unsigned*)(ws + kOffAcc + 16);
  const float4* planes = (const float4*)(ws + kOffPlanes);
  double* zp = (double*)(ws + kOffZP);
  float2* zm = (float2*)(ws + kOffZM);
  const float4* ptsraw = (const float4*)(ws + kOffPts);

  const int b = blockIdx.x, t = threadIdx.x;
  const int lane = t & 63, wid = t >> 6;
  const float th = get_thresh(*epoch);
  const float maxv = __uint_as_float((unsigned)*maxvBits);

  // best plane + rotation derived per block (cheap, uniform)
  int best = 1023 - (int)(*selkeyp & 1023u);
  float4 pl = planes[best];
  const float a = pl.x, bb = pl.y, c = pl.z, d = pl.w;
  float n2 = a * a + bb * bb + c * c;
  float cos_t = c / sqrtf(n2);
  float sin_t = sqrtf((a * a + bb * bb) / n2);
  float sab = sqrtf(a * a + bb * bb);
  float u1 = bb / sab, u2 = -a / sab;
  const float r0 = -u2 * sin_t, r1 = u1 * sin_t, r2 = cos_t, tz = d / c;

  __shared__ double sD0[4];
  __shared__ int sI0[4];
  __shared__ float sF0[4], sF1[4];

  double sz = 0.0; int ic = 0; float zmx = -INFINITY, zmn = -INFINITY;  // zmn = max(-zc)
  {
    float4 rw = ptsraw[b * 256 + t];
    float qx = rw.x / maxv, qy = rw.y / maxv, qz = rw.z / maxv;
    // identical per-lane chain to k_count's pk_fma halves
    float dist = fmaf(qx, a, fmaf(qy, bb, fmaf(qz, c, d)));
    if (fabsf(dist) <= th) {
      float zc = fmaf(qx, r0, fmaf(qy, r1, (qz + tz) * r2));
      sz = (double)zc; ic = 1; zmx = zc; zmn = -zc;
    }
  }
  for (int o = 32; o; o >>= 1) {
    sz += __shfl_down(sz, o); ic += __shfl_down(ic, o);
    zmx = fmaxf(zmx, __shfl_down(zmx, o));
    zmn = fmaxf(zmn, __shfl_down(zmn, o));
  }
  if (lane == 0) { sD0[wid] = sz; sI0[wid] = ic; sF0[wid] = zmx; sF1[wid] = zmn; }
  __syncthreads();
  if (t == 0) {
    zp[(size_t)b * 2 + 0] = sD0[0]+sD0[1]+sD0[2]+sD0[3];
    zp[(size_t)b * 2 + 1] = (double)(sI0[0]+sI0[1]+sI0[2]+sI0[3]);
    float bmx = fmaxf(fmaxf(sF0[0], sF0[1]), fmaxf(sF0[2], sF0[3]));
    float bmn = fmaxf(fmaxf(sF1[0], sF1[1]), fmaxf(sF1[2], sF1[3]));
    zm[b] = make_float2(bmx, bmn);
  }
}

// ================= K6: final pmdg (1 block) =================
__global__ __launch_bounds__(256) void k_final(float* __restrict__ out,
                                               char* __restrict__ ws) {
  const double* loss17p = (const double*)(ws + kOffAcc + 8);
  const double* zp = (const double*)(ws + kOffZP);
  const float2* zm = (const float2*)(ws + kOffZM);

  const int t = threadIdx.x;
  const int lane = t & 63, wid = t >> 6;

  __shared__ double sD0[4];
  __shared__ int sI0[4];
  __shared__ float sF0[4], sF1[4];

  double gs = 0.0; int gi = 0; float gmx = -INFINITY, gmn = -INFINITY;
  for (int r = t; r < kB5; r += 256) {
    gs += zp[(size_t)r * 2 + 0];
    gi += (int)zp[(size_t)r * 2 + 1];
    float2 mm = zm[r];
    gmx = fmaxf(gmx, mm.x);
    gmn = fmaxf(gmn, mm.y);
  }
  for (int o = 32; o; o >>= 1) {
    gs += __shfl_down(gs, o); gi += __shfl_down(gi, o);
    gmx = fmaxf(gmx, __shfl_down(gmx, o));
    gmn = fmaxf(gmn, __shfl_down(gmn, o));
  }
  if (lane == 0) { sD0[wid] = gs; sI0[wid] = gi; sF0[wid] = gmx; sF1[wid] = gmn; }
  __syncthreads();
  if (t == 0) {
    double S = sD0[0]+sD0[1]+sD0[2]+sD0[3];
    int IC = sI0[0]+sI0[1]+sI0[2]+sI0[3];
    float MX = fmaxf(fmaxf(sF0[0], sF0[1]), fmaxf(sF0[2], sF0[3]));
    float MN = fmaxf(fmaxf(sF1[0], sF1[1]), fmaxf(sF1[2], sF1[3]));
    double below = 0.0, above = 0.0;
    if (IC > 0) {
      double icd = (double)IC;
      double mean = S / icd;
      below = (double)MX - mean;    // sum(|zc - zmax|)/icnt  (all zc <= zmax)
      above = mean - (double)(-MN); // sum(|zc - zmin|)/icnt
    }
    if (above == 0.0) above = 1e-7;
    double pmdg = 1000.0 * (above + below);
    out[4] = (float)pmdg;
    out[6] = (float)(*loss17p + pmdg);
  }
}

}  // namespace

extern "C" void kernel_launch(void* const* d_in, const int* in_sizes, int n_in,
                              void* d_out, int out_size, void* d_ws, size_t ws_size,
                              hipStream_t stream) {
  (void)in_sizes; (void)n_in; (void)out_size; (void)ws_size;
  const float* fake = (const float*)d_in[0];
  const float* real = (const float*)d_in[1];
  const int* epoch = (const int*)d_in[2];
  float* out = (float*)d_out;
  char* ws = (char*)d_ws;

  k_stats<<<kB1, 256, 0, stream>>>(fake, real, ws);
  k_scalars_planes<<<5, 256, 0, stream>>>(fake, out, ws);
  k_count<<<kB3, 256, 0, stream>>>(epoch, ws);
  k_select<<<16, 256, 0, stream>>>(ws);
  k_zc<<<kB5, 256, 0, stream>>>(epoch, ws);
  k_final<<<1, 256, 0, stream>>>(out, ws);
}